// Round 5
// baseline (1792.822 us; speedup 1.0000x reference)
//
#include <hip/hip_runtime.h>
#include <math.h>

#define T_STEPS 4096
#define B_N     512

// 20 floats = 80 bytes, five float4 loads per (t,b) step.
struct alignas(16) Pk {
  float KU1, KU2, KU3, KU4;   // kp*u_i/tau2^2
  float A,   mn,  mx,  cthr;  // A=-2*damp*tau2 ; cthr = tau*kTh/mB
  float cdym, cdxm, cq, cdx;  // tau*kTh*dym/IBxx ; tau*kTh*dxm/IByy ; tau*kTo/IBzz ; tau*Cd/mB
  float cA,  cB,  cC,  cD;    // tau*(IByy-IBzz)/IBxx ; tau*uP*IRzz/IBxx ; tau*(IBzz-IBxx)/IByy ; tau*uP*IRzz/IByy
  float cE,  label, pad0, pad1; // tau*(IBxx-IByy)/IBzz
};

union PkU { Pk p; float4 v[5]; };

__device__ __forceinline__ float sc_ref(float g, float base) {
  return (1.0f + (0.5f - g) * 0.95f) * base;
}

__device__ __forceinline__ Pk computePk(size_t i,
    const float* __restrict__ logits,
    const float* __restrict__ u1, const float* __restrict__ u2,
    const float* __restrict__ u3, const float* __restrict__ u4,
    const float* __restrict__ mxM, const float* __restrict__ mnM,
    const float* __restrict__ labels) {
  const float4* lg = (const float4*)logits + i * 3;
  float4 l0 = lg[0], l1 = lg[1], l2 = lg[2];
  float dxm  = sc_ref(l0.x, 0.16f);
  float dym  = sc_ref(l0.y, 0.16f);
  float IBxx = sc_ref(l0.w, 0.0123f);
  float IByy = sc_ref(l1.x, 0.0123f);
  float IBzz = sc_ref(l1.y, 0.0123f);
  float Cd   = sc_ref(l1.z, 0.1f);
  float kTh  = sc_ref(l1.w, 1.076e-05f);
  float kTo  = sc_ref(l2.x, 1.632e-07f);
  float tau2 = sc_ref(l2.y, 0.015f);
  float kp   = sc_ref(l2.z, 1.0f);
  float damp = sc_ref(l2.w, 1.0f);
  const float tau = 0.005f;
  const float tauOverMb = tau / 1.2f;
  Pk p;
  float K = kp / (tau2 * tau2);
  p.KU1 = K * u1[i];  p.KU2 = K * u2[i];  p.KU3 = K * u3[i];  p.KU4 = K * u4[i];
  p.A   = -2.0f * damp * tau2;
  p.mn  = mnM[i];  p.mx = mxM[i];
  p.cthr = kTh * tauOverMb;
  float tx = tau / IBxx, ty = tau / IByy, tz = tau / IBzz;
  p.cdym = kTh * dym * tx;
  p.cdxm = kTh * dxm * ty;
  p.cq   = kTo * tz;
  p.cdx  = Cd * tauOverMb;
  p.cA = (IByy - IBzz) * tx;
  p.cB = 1e-04f * tx;
  p.cC = (IBzz - IBxx) * ty;
  p.cD = 1e-04f * ty;
  p.cE = (IBxx - IByy) * tz;
  p.label = labels[i];
  p.pad0 = 0.f; p.pad1 = 0.f;
  return p;
}

struct Carry {
  float xz, q0, q1, q2, q3, zd, pv, qv, rv;
  float w1, w2, w3, w4, wd1, wd2, wd3, wd4;
};

__device__ __forceinline__ void stepOne(Carry& c, const Pk& p, float& facc) {
  const float TAU = 0.005f, HTAU = 0.0025f, TAUG = 0.04905f;
  float wdd1 = fmaf(p.A, c.wd1, p.KU1) - c.w1;
  float wdd2 = fmaf(p.A, c.wd2, p.KU2) - c.w2;
  float wdd3 = fmaf(p.A, c.wd3, p.KU3) - c.w3;
  float wdd4 = fmaf(p.A, c.wd4, p.KU4) - c.w4;
  float w1c = fminf(fmaxf(c.w1, p.mn), p.mx);
  float w2c = fminf(fmaxf(c.w2, p.mn), p.mx);
  float w3c = fminf(fmaxf(c.w3, p.mn), p.mx);
  float w4c = fminf(fmaxf(c.w4, p.mn), p.mx);
  float s1 = w1c * w1c, s2 = w2c * w2c, s3 = w3c * w3c, s4 = w4c * w4c;
  float sA = s1 + s3, sB = s2 + s4;
  float ssum = sA + sB;
  float dymd = (s1 + s4) - (s2 + s3);
  float dxmd = (s1 + s2) - (s3 + s4);
  float dqd  = sB - sA;
  float Thr2 = p.cthr * ssum;
  float qq = fmaf(c.q0, c.q0, c.q3 * c.q3) - fmaf(c.q1, c.q1, c.q2 * c.q2);
  float zdm = c.zd * fabsf(c.zd);
  float nzd = fmaf(-p.cdx, zdm, c.zd);
  nzd = fmaf(Thr2, qq, nzd) - TAUG;
  float t0 = fmaf(c.pv, c.q1, fmaf(c.qv, c.q2,  c.rv * c.q3));
  float t1 = fmaf(c.pv, c.q0, fmaf(-c.qv, c.q3, c.rv * c.q2));
  float t2 = fmaf(c.pv, c.q3, fmaf(c.qv, c.q0, -(c.rv * c.q1)));
  float t3 = fmaf(-c.pv, c.q2, fmaf(c.qv, c.q1, c.rv * c.q0));
  float nq0 = fmaf(-HTAU, t0, c.q0);
  float nq1 = fmaf( HTAU, t1, c.q1);
  float nq2 = fmaf( HTAU, t2, c.q2);
  float nq3 = fmaf( HTAU, t3, c.q3);
  float wsum = (w1c - w2c) + (w3c - w4c);
  float npv = fmaf(p.cA, c.qv * c.rv, c.pv);
  npv = fmaf(-p.cB, wsum * c.qv, npv);
  npv = fmaf(p.cdym, dymd, npv);
  float nqv = fmaf(p.cC, c.pv * c.rv, c.qv);
  nqv = fmaf(p.cD, wsum * c.pv, nqv);
  nqv = fmaf(p.cdxm, dxmd, nqv);
  float nrv = fmaf(p.cE, c.pv * c.qv, c.rv);
  nrv = fmaf(p.cq, dqd, nrv);
  float nxz = fmaf(TAU, nzd, c.xz);
  float d = nxz - c.xz;
  // |d|<=400 is false for NaN/Inf nxz, so it subsumes the isfinite check
  bool ok = (fabsf(d) <= 400.0f);
  float xznew = ok ? nxz : c.xz;
  float e = xznew - p.label;
  facc = fmaf(e, e, facc);
  c.w1 = fmaf(TAU, c.wd1, w1c);
  c.w2 = fmaf(TAU, c.wd2, w2c);
  c.w3 = fmaf(TAU, c.wd3, w3c);
  c.w4 = fmaf(TAU, c.wd4, w4c);
  c.wd1 = fmaf(TAU, wdd1, c.wd1);
  c.wd2 = fmaf(TAU, wdd2, c.wd2);
  c.wd3 = fmaf(TAU, wdd3, c.wd3);
  c.wd4 = fmaf(TAU, wdd4, c.wd4);
  c.q0 = nq0; c.q1 = nq1; c.q2 = nq2; c.q3 = nq3;
  c.pv = npv; c.qv = nqv; c.rv = nrv;
  c.zd = nzd; c.xz = xznew;
}

__device__ __forceinline__ void gload_lds16(const void* g, void* l) {
  __builtin_amdgcn_global_load_lds(
      (const __attribute__((address_space(1))) void*)g,
      (__attribute__((address_space(3))) void*)l, 16, 0, 0);
}

// ---- kernel 1: partial sums of kTh over T*B (deterministic tree) ----
__global__ void k_kth(const float* __restrict__ logits, float* __restrict__ partial) {
  __shared__ float sm[256];
  float a = 0.f;
  const int n = T_STEPS * B_N;
  for (int i = blockIdx.x * 256 + threadIdx.x; i < n; i += 1024 * 256)
    a += (1.0f + (0.5f - logits[(size_t)i * 12 + 7]) * 0.95f) * 1.076e-05f;
  sm[threadIdx.x] = a; __syncthreads();
  for (int s = 128; s; s >>= 1) {
    if (threadIdx.x < s) sm[threadIdx.x] += sm[threadIdx.x + s];
    __syncthreads();
  }
  if (threadIdx.x == 0) partial[blockIdx.x] = sm[0];
}

// ---- kernel 2: finalize hover ----
__global__ void k_hover(const float* __restrict__ partial, float* __restrict__ hover) {
  __shared__ float sm[1024];
  sm[threadIdx.x] = partial[threadIdx.x];
  __syncthreads();
  for (int s = 512; s; s >>= 1) {
    if (threadIdx.x < s) sm[threadIdx.x] += sm[threadIdx.x + s];
    __syncthreads();
  }
  if (threadIdx.x == 0) {
    float mean = sm[0] * (1.0f / 2097152.0f);
    float h = 1.2f * 9.81f / (4.0f * mean + 1e-12f);
    hover[0] = sqrtf(fmaxf(h, 1e-06f));
  }
}

// ---- kernel 3: per-(t,b) parameter precompute (fully parallel) ----
__global__ void k_pre(const float* __restrict__ logits,
                      const float* __restrict__ u1, const float* __restrict__ u2,
                      const float* __restrict__ u3, const float* __restrict__ u4,
                      const float* __restrict__ mxM, const float* __restrict__ mnM,
                      const float* __restrict__ labels, Pk* __restrict__ pack) {
  size_t i = (size_t)blockIdx.x * 256 + threadIdx.x;  // 8192*256 == T*B exactly
  PkU u;
  u.p = computePk(i, logits, u1, u2, u3, u4, mxM, mnM, labels);
  float4* dst = (float4*)(pack + i);
  #pragma unroll
  for (int k = 0; k < 5; ++k) dst[k] = u.v[k];
}

// ---- kernel 4: serial scan; LDS dbuf staging; distance-2 4-set rotation ----
__global__ __launch_bounds__(32, 1) void k_sim2(
    const Pk* __restrict__ pack,
    const float* __restrict__ labels,
    const float* __restrict__ hoverp, double* __restrict__ bsum) {
  __shared__ float4 lds[2 * 8 * 5 * 32];   // 40 KB, flat: (((buf*8+slot)*5+k)*32+lane)
  const int lane = threadIdx.x;
  const int b = blockIdx.x * 32 + lane;    // 16 blocks x 32 lanes = 512
  float hv = hoverp[0];
  Carry c;
  c.xz = 0.f; c.q0 = 1.f; c.q1 = 0.f; c.q2 = 0.f; c.q3 = 0.f;
  c.zd = 0.f; c.pv = 0.f; c.qv = 0.f; c.rv = 0.f;
  c.w1 = hv; c.w2 = hv; c.w3 = hv; c.w4 = hv;
  c.wd1 = 0.f; c.wd2 = 0.f; c.wd3 = 0.f; c.wd4 = 0.f;
  float l0 = labels[b];
  double acc = (double)l0 * (double)l0;    // t=0 term: pred_z[0]=0

  const char* packb = (const char*)pack + (size_t)b * sizeof(Pk);

// ds_read set SET <- lds[BUF][SLOT][k][lane]; BUF/SLOT compile-time ->
// one shared vaddr (lane*16) + immediate offsets, 5x ds_read_b128.
#define PREF(SET, BUF, SLOT) do {                                      \
    _Pragma("unroll")                                                  \
    for (int k = 0; k < 5; ++k)                                        \
      (SET).v[k] = lds[((((BUF)*8+(SLOT))*5)+k)*32 + lane];            \
  } while (0)

// stage chunk CH1 (8 steps x 5 xfers) into buffer BUFN via async DMA
#define STAGE(CH1, BUFN) do {                                          \
    int base_t = 1 + (CH1) * 8;                                        \
    _Pragma("unroll")                                                  \
    for (int s = 0; s < 8; ++s) {                                      \
      int t = base_t + s; t = (t > T_STEPS-1) ? (T_STEPS-1) : t;       \
      const char* src = packb + (size_t)t * (B_N * sizeof(Pk));        \
      _Pragma("unroll")                                                \
      for (int k = 0; k < 5; ++k)                                      \
        gload_lds16(src + 16*k, (void*)&lds[((((BUFN)*8+s)*5)+k)*32]); \
    }                                                                  \
  } while (0)

// full drain: chunk staged >=6 steps ago (~1100cy > ~900cy HBM) -> ~free.
// sched_barrier pins following ds_reads/uses behind the wait (rule #18).
#define VGATE do { asm volatile("s_waitcnt vmcnt(0)" ::: "memory");    \
                   __builtin_amdgcn_sched_barrier(0); } while (0)

// One chunk: stage next chunk, 8 steps with distance-2 prefetch rotation
// (use set s%4, prefetch step+2 into set (s+2)%4; 8%4==0 -> chunk-invariant).
// Gate before the first read of BUFN (s=6).
#define CHUNK_BODY(CH, BUF, BUFN) do {                                 \
    float facc = 0.f;                                                  \
    STAGE((CH)+1, BUFN);                                               \
    PREF(SC,BUF,2); stepOne(c, SA.p, facc);                            \
    PREF(SD,BUF,3); stepOne(c, SB.p, facc);                            \
    PREF(SA,BUF,4); stepOne(c, SC.p, facc);                            \
    PREF(SB,BUF,5); stepOne(c, SD.p, facc);                            \
    PREF(SC,BUF,6); stepOne(c, SA.p, facc);                            \
    PREF(SD,BUF,7); stepOne(c, SB.p, facc);                            \
    VGATE;                                                             \
    PREF(SA,BUFN,0); stepOne(c, SC.p, facc);                           \
    PREF(SB,BUFN,1); stepOne(c, SD.p, facc);                           \
    acc += (double)facc;                                               \
  } while (0)

  PkU SA, SB, SC, SD;
  STAGE(0, 0);                 // prologue: chunk 0 -> buf 0
  VGATE;
  PREF(SA, 0, 0); PREF(SB, 0, 1);

  for (int ch = 0; ch < 510; ch += 2) {   // chunks 0..509, bufs compile-time
    CHUNK_BODY(ch,     0, 1);
    CHUNK_BODY(ch + 1, 1, 0);
  }
  CHUNK_BODY(510, 0, 1);       // stages chunk 511 into buf 1; drains it

  { // epilogue: chunk 511 resident in buf 1; steps t = 4089..4095 (slots 0..6)
    float facc = 0.f;
    PREF(SC,1,2); stepOne(c, SA.p, facc);   // 4089
    PREF(SD,1,3); stepOne(c, SB.p, facc);   // 4090
    PREF(SA,1,4); stepOne(c, SC.p, facc);   // 4091
    PREF(SB,1,5); stepOne(c, SD.p, facc);   // 4092
    PREF(SC,1,6); stepOne(c, SA.p, facc);   // 4093
    stepOne(c, SB.p, facc);                 // 4094
    stepOne(c, SC.p, facc);                 // 4095
    acc += (double)facc;
  }
  bsum[b] = acc;
#undef PREF
#undef STAGE
#undef VGATE
#undef CHUNK_BODY
}

// ---- fallback (no workspace): inline params, no staging ----
__global__ __launch_bounds__(64, 1) void k_sim_fb(
    const float* __restrict__ logits,
    const float* __restrict__ u1, const float* __restrict__ u2,
    const float* __restrict__ u3, const float* __restrict__ u4,
    const float* __restrict__ mxM, const float* __restrict__ mnM,
    const float* __restrict__ labels,
    const float* __restrict__ hoverp, double* __restrict__ bsum) {
  int b = blockIdx.x * 64 + threadIdx.x;
  float hv = hoverp[0];
  Carry c;
  c.xz = 0.f; c.q0 = 1.f; c.q1 = 0.f; c.q2 = 0.f; c.q3 = 0.f;
  c.zd = 0.f; c.pv = 0.f; c.qv = 0.f; c.rv = 0.f;
  c.w1 = hv; c.w2 = hv; c.w3 = hv; c.w4 = hv;
  c.wd1 = 0.f; c.wd2 = 0.f; c.wd3 = 0.f; c.wd4 = 0.f;
  float l0 = labels[b];
  double acc = (double)l0 * (double)l0;
  for (int t = 1; t < T_STEPS; ++t) {
    Pk p = computePk((size_t)t * B_N + b, logits, u1, u2, u3, u4, mxM, mnM, labels);
    float facc = 0.f;
    stepOne(c, p, facc);
    acc += (double)facc;
  }
  bsum[b] = acc;
}

// ---- kernel 5: final deterministic reduce ----
__global__ void k_final(const double* __restrict__ bsum, float* __restrict__ out) {
  __shared__ double sm[512];
  sm[threadIdx.x] = bsum[threadIdx.x];
  __syncthreads();
  for (int s = 256; s; s >>= 1) {
    if (threadIdx.x < s) sm[threadIdx.x] += sm[threadIdx.x + s];
    __syncthreads();
  }
  if (threadIdx.x == 0) out[0] = (float)(sm[0] * (1.0 / 2097152.0));
}

extern "C" void kernel_launch(void* const* d_in, const int* in_sizes, int n_in,
                              void* d_out, int out_size, void* d_ws, size_t ws_size,
                              hipStream_t stream) {
  const float* labels = (const float*)d_in[0];
  const float* logits = (const float*)d_in[1];
  const float* u1 = (const float*)d_in[2];
  const float* u2 = (const float*)d_in[3];
  const float* u3 = (const float*)d_in[4];
  const float* u4 = (const float*)d_in[5];
  const float* mxM = (const float*)d_in[6];
  const float* mnM = (const float*)d_in[7];
  float* out = (float*)d_out;

  char* ws = (char*)d_ws;
  float*  hover   = (float*)(ws);
  float*  partial = (float*)(ws + 256);
  double* bsum    = (double*)(ws + 8192);
  Pk*     pack    = (Pk*)(ws + 16384);
  size_t need = 16384 + (size_t)T_STEPS * B_N * sizeof(Pk);
  bool pre = (ws_size >= need);

  k_kth  <<<1024, 256, 0, stream>>>(logits, partial);
  k_hover<<<1, 1024, 0, stream>>>(partial, hover);
  if (pre) {
    k_pre<<<8192, 256, 0, stream>>>(logits, u1, u2, u3, u4, mxM, mnM, labels, pack);
    k_sim2<<<16, 32, 0, stream>>>(pack, labels, hover, bsum);
  } else {
    k_sim_fb<<<8, 64, 0, stream>>>(logits, u1, u2, u3, u4, mxM, mnM, labels, hover, bsum);
  }
  k_final<<<1, 512, 0, stream>>>(bsum, out);
}

// Round 6
// 1496.345 us; speedup vs baseline: 1.1981x; 1.1981x over previous
//
#include <hip/hip_runtime.h>
#include <math.h>

#define T_STEPS 4096
#define B_N     512

// 20 floats = 80 bytes, five float4 loads per (t,b) step.
struct alignas(16) Pk {
  float KU1, KU2, KU3, KU4;   // kp*u_i/tau2^2
  float A,   mn,  mx,  cthr;  // A=-2*damp*tau2 ; cthr = tau*kTh/mB
  float cdym, cdxm, cq, cdx;  // tau*kTh*dym/IBxx ; tau*kTh*dxm/IByy ; tau*kTo/IBzz ; tau*Cd/mB
  float cA,  cB,  cC,  cD;    // tau*(IByy-IBzz)/IBxx ; tau*uP*IRzz/IBxx ; tau*(IBzz-IBxx)/IByy ; tau*uP*IRzz/IByy
  float cE,  label, pad0, pad1; // tau*(IBxx-IByy)/IBzz
};

union PkU { Pk p; float4 v[5]; };

__device__ __forceinline__ float sc_ref(float g, float base) {
  return (1.0f + (0.5f - g) * 0.95f) * base;
}

__device__ __forceinline__ Pk computePk(size_t i,
    const float* __restrict__ logits,
    const float* __restrict__ u1, const float* __restrict__ u2,
    const float* __restrict__ u3, const float* __restrict__ u4,
    const float* __restrict__ mxM, const float* __restrict__ mnM,
    const float* __restrict__ labels) {
  const float4* lg = (const float4*)logits + i * 3;
  float4 l0 = lg[0], l1 = lg[1], l2 = lg[2];
  float dxm  = sc_ref(l0.x, 0.16f);
  float dym  = sc_ref(l0.y, 0.16f);
  float IBxx = sc_ref(l0.w, 0.0123f);
  float IByy = sc_ref(l1.x, 0.0123f);
  float IBzz = sc_ref(l1.y, 0.0123f);
  float Cd   = sc_ref(l1.z, 0.1f);
  float kTh  = sc_ref(l1.w, 1.076e-05f);
  float kTo  = sc_ref(l2.x, 1.632e-07f);
  float tau2 = sc_ref(l2.y, 0.015f);
  float kp   = sc_ref(l2.z, 1.0f);
  float damp = sc_ref(l2.w, 1.0f);
  const float tau = 0.005f;
  const float tauOverMb = tau / 1.2f;
  Pk p;
  float K = kp / (tau2 * tau2);
  p.KU1 = K * u1[i];  p.KU2 = K * u2[i];  p.KU3 = K * u3[i];  p.KU4 = K * u4[i];
  p.A   = -2.0f * damp * tau2;
  p.mn  = mnM[i];  p.mx = mxM[i];
  p.cthr = kTh * tauOverMb;
  float tx = tau / IBxx, ty = tau / IByy, tz = tau / IBzz;
  p.cdym = kTh * dym * tx;
  p.cdxm = kTh * dxm * ty;
  p.cq   = kTo * tz;
  p.cdx  = Cd * tauOverMb;
  p.cA = (IByy - IBzz) * tx;
  p.cB = 1e-04f * tx;
  p.cC = (IBzz - IBxx) * ty;
  p.cD = 1e-04f * ty;
  p.cE = (IBxx - IByy) * tz;
  p.label = labels[i];
  p.pad0 = 0.f; p.pad1 = 0.f;
  return p;
}

struct Carry {
  float xz, q0, q1, q2, q3, zd, pv, qv, rv;
  float w1, w2, w3, w4, wd1, wd2, wd3, wd4;
};

__device__ __forceinline__ void stepOne(Carry& c, const Pk& p, float& facc) {
  const float TAU = 0.005f, HTAU = 0.0025f, TAUG = 0.04905f;
  float wdd1 = fmaf(p.A, c.wd1, p.KU1) - c.w1;
  float wdd2 = fmaf(p.A, c.wd2, p.KU2) - c.w2;
  float wdd3 = fmaf(p.A, c.wd3, p.KU3) - c.w3;
  float wdd4 = fmaf(p.A, c.wd4, p.KU4) - c.w4;
  float w1c = fminf(fmaxf(c.w1, p.mn), p.mx);
  float w2c = fminf(fmaxf(c.w2, p.mn), p.mx);
  float w3c = fminf(fmaxf(c.w3, p.mn), p.mx);
  float w4c = fminf(fmaxf(c.w4, p.mn), p.mx);
  float s1 = w1c * w1c, s2 = w2c * w2c, s3 = w3c * w3c, s4 = w4c * w4c;
  float sA = s1 + s3, sB = s2 + s4;
  float ssum = sA + sB;
  float dymd = (s1 + s4) - (s2 + s3);
  float dxmd = (s1 + s2) - (s3 + s4);
  float dqd  = sB - sA;
  float Thr2 = p.cthr * ssum;
  float qq = fmaf(c.q0, c.q0, c.q3 * c.q3) - fmaf(c.q1, c.q1, c.q2 * c.q2);
  float zdm = c.zd * fabsf(c.zd);
  float nzd = fmaf(-p.cdx, zdm, c.zd);
  nzd = fmaf(Thr2, qq, nzd) - TAUG;
  float t0 = fmaf(c.pv, c.q1, fmaf(c.qv, c.q2,  c.rv * c.q3));
  float t1 = fmaf(c.pv, c.q0, fmaf(-c.qv, c.q3, c.rv * c.q2));
  float t2 = fmaf(c.pv, c.q3, fmaf(c.qv, c.q0, -(c.rv * c.q1)));
  float t3 = fmaf(-c.pv, c.q2, fmaf(c.qv, c.q1, c.rv * c.q0));
  float nq0 = fmaf(-HTAU, t0, c.q0);
  float nq1 = fmaf( HTAU, t1, c.q1);
  float nq2 = fmaf( HTAU, t2, c.q2);
  float nq3 = fmaf( HTAU, t3, c.q3);
  float wsum = (w1c - w2c) + (w3c - w4c);
  float npv = fmaf(p.cA, c.qv * c.rv, c.pv);
  npv = fmaf(-p.cB, wsum * c.qv, npv);
  npv = fmaf(p.cdym, dymd, npv);
  float nqv = fmaf(p.cC, c.pv * c.rv, c.qv);
  nqv = fmaf(p.cD, wsum * c.pv, nqv);
  nqv = fmaf(p.cdxm, dxmd, nqv);
  float nrv = fmaf(p.cE, c.pv * c.qv, c.rv);
  nrv = fmaf(p.cq, dqd, nrv);
  float nxz = fmaf(TAU, nzd, c.xz);
  float d = nxz - c.xz;
  // |d|<=400 is false for NaN/Inf nxz, so it subsumes the isfinite check
  bool ok = (fabsf(d) <= 400.0f);
  float xznew = ok ? nxz : c.xz;
  float e = xznew - p.label;
  facc = fmaf(e, e, facc);
  c.w1 = fmaf(TAU, c.wd1, w1c);
  c.w2 = fmaf(TAU, c.wd2, w2c);
  c.w3 = fmaf(TAU, c.wd3, w3c);
  c.w4 = fmaf(TAU, c.wd4, w4c);
  c.wd1 = fmaf(TAU, wdd1, c.wd1);
  c.wd2 = fmaf(TAU, wdd2, c.wd2);
  c.wd3 = fmaf(TAU, wdd3, c.wd3);
  c.wd4 = fmaf(TAU, wdd4, c.wd4);
  c.q0 = nq0; c.q1 = nq1; c.q2 = nq2; c.q3 = nq3;
  c.pv = npv; c.qv = nqv; c.rv = nrv;
  c.zd = nzd; c.xz = xznew;
}

__device__ __forceinline__ void gload_lds16(const void* g, void* l) {
  __builtin_amdgcn_global_load_lds(
      (const __attribute__((address_space(1))) void*)g,
      (__attribute__((address_space(3))) void*)l, 16, 0, 0);
}

// ---- kernel 1: partial sums of kTh over T*B (deterministic tree) ----
__global__ void k_kth(const float* __restrict__ logits, float* __restrict__ partial) {
  __shared__ float sm[256];
  float a = 0.f;
  const int n = T_STEPS * B_N;
  for (int i = blockIdx.x * 256 + threadIdx.x; i < n; i += 1024 * 256)
    a += (1.0f + (0.5f - logits[(size_t)i * 12 + 7]) * 0.95f) * 1.076e-05f;
  sm[threadIdx.x] = a; __syncthreads();
  for (int s = 128; s; s >>= 1) {
    if (threadIdx.x < s) sm[threadIdx.x] += sm[threadIdx.x + s];
    __syncthreads();
  }
  if (threadIdx.x == 0) partial[blockIdx.x] = sm[0];
}

// ---- kernel 2: finalize hover ----
__global__ void k_hover(const float* __restrict__ partial, float* __restrict__ hover) {
  __shared__ float sm[1024];
  sm[threadIdx.x] = partial[threadIdx.x];
  __syncthreads();
  for (int s = 512; s; s >>= 1) {
    if (threadIdx.x < s) sm[threadIdx.x] += sm[threadIdx.x + s];
    __syncthreads();
  }
  if (threadIdx.x == 0) {
    float mean = sm[0] * (1.0f / 2097152.0f);
    float h = 1.2f * 9.81f / (4.0f * mean + 1e-12f);
    hover[0] = sqrtf(fmaxf(h, 1e-06f));
  }
}

// ---- kernel 3: per-(t,b) parameter precompute (fully parallel) ----
__global__ void k_pre(const float* __restrict__ logits,
                      const float* __restrict__ u1, const float* __restrict__ u2,
                      const float* __restrict__ u3, const float* __restrict__ u4,
                      const float* __restrict__ mxM, const float* __restrict__ mnM,
                      const float* __restrict__ labels, Pk* __restrict__ pack) {
  size_t i = (size_t)blockIdx.x * 256 + threadIdx.x;  // 8192*256 == T*B exactly
  PkU u;
  u.p = computePk(i, logits, u1, u2, u3, u4, mxM, mnM, labels);
  float4* dst = (float4*)(pack + i);
  #pragma unroll
  for (int k = 0; k < 5; ++k) dst[k] = u.v[k];
}

// ---- kernel 4: serial scan; triple-buffered LDS; stage 2 chunks ahead ----
__global__ __launch_bounds__(64, 1) void k_sim3(
    const Pk* __restrict__ pack,
    const float* __restrict__ labels,
    const float* __restrict__ hoverp, double* __restrict__ bsum) {
  __shared__ float4 lds[3 * 8 * 5 * 64];   // 120 KB: (((buf*8+slot)*5+k)*64+lane)
  const int lane = threadIdx.x;
  const int b = blockIdx.x * 64 + lane;    // 8 blocks x 64 lanes = 512
  float hv = hoverp[0];
  Carry c;
  c.xz = 0.f; c.q0 = 1.f; c.q1 = 0.f; c.q2 = 0.f; c.q3 = 0.f;
  c.zd = 0.f; c.pv = 0.f; c.qv = 0.f; c.rv = 0.f;
  c.w1 = hv; c.w2 = hv; c.w3 = hv; c.w4 = hv;
  c.wd1 = 0.f; c.wd2 = 0.f; c.wd3 = 0.f; c.wd4 = 0.f;
  float l0 = labels[b];
  double acc = (double)l0 * (double)l0;    // t=0 term: pred_z[0]=0

  const char* packb = (const char*)pack + (size_t)b * sizeof(Pk);

// ds_read set SET <- lds[BUF][SLOT][k][lane]; BUF/SLOT compile-time ->
// one shared vaddr (lane*16) + immediate offsets, 5x ds_read_b128.
#define PREF(SET, BUF, SLOT) do {                                      \
    _Pragma("unroll")                                                  \
    for (int k = 0; k < 5; ++k)                                        \
      (SET).v[k] = lds[((((BUF)*8+(SLOT))*5)+k)*64 + lane];            \
  } while (0)

// stage chunk CH1 (8 steps x 5 xfers, 40 loads) into buffer BUFN (literal)
#define STAGE(CH1, BUFN) do {                                          \
    int base_t = 1 + (CH1) * 8;                                        \
    _Pragma("unroll")                                                  \
    for (int s = 0; s < 8; ++s) {                                      \
      int t = base_t + s; t = (t > T_STEPS-1) ? (T_STEPS-1) : t;       \
      const char* src = packb + (size_t)t * (B_N * sizeof(Pk));        \
      _Pragma("unroll")                                                \
      for (int k = 0; k < 5; ++k)                                      \
        gload_lds16(src + 16*k, (void*)&lds[((((BUFN)*8+s)*5)+k)*64]); \
    }                                                                  \
  } while (0)

// counted wait: exactly one older chunk (40 loads) must retire; the newer
// in-flight chunk stays outstanding. sched_barrier pins later ds_reads/uses
// behind the wait (rule #18).
#define WAIT40 do { asm volatile("s_waitcnt vmcnt(40)" ::: "memory");  \
                    __builtin_amdgcn_sched_barrier(0); } while (0)
#define WAIT0  do { asm volatile("s_waitcnt vmcnt(0)" ::: "memory");   \
                    __builtin_amdgcn_sched_barrier(0); } while (0)

// 8 steps from BUF with 4-set distance-2 rotation (indices all static)
#define RUN8(BUF) do {                                                 \
    float facc = 0.f;                                                  \
    PREF(SA,BUF,0); PREF(SB,BUF,1);                                    \
    PREF(SC,BUF,2); stepOne(c, SA.p, facc);                            \
    PREF(SD,BUF,3); stepOne(c, SB.p, facc);                            \
    PREF(SA,BUF,4); stepOne(c, SC.p, facc);                            \
    PREF(SB,BUF,5); stepOne(c, SD.p, facc);                            \
    PREF(SC,BUF,6); stepOne(c, SA.p, facc);                            \
    PREF(SD,BUF,7); stepOne(c, SB.p, facc);                            \
    stepOne(c, SC.p, facc);                                            \
    stepOne(c, SD.p, facc);                                            \
    acc += (double)facc;                                               \
  } while (0)

// 7 steps (slots 0..6) for the final chunk (t = 4089..4095)
#define RUN7(BUF) do {                                                 \
    float facc = 0.f;                                                  \
    PREF(SA,BUF,0); PREF(SB,BUF,1);                                    \
    PREF(SC,BUF,2); stepOne(c, SA.p, facc);                            \
    PREF(SD,BUF,3); stepOne(c, SB.p, facc);                            \
    PREF(SA,BUF,4); stepOne(c, SC.p, facc);                            \
    PREF(SB,BUF,5); stepOne(c, SD.p, facc);                            \
    PREF(SC,BUF,6); stepOne(c, SA.p, facc);                            \
    stepOne(c, SB.p, facc);                                            \
    stepOne(c, SC.p, facc);                                            \
    acc += (double)facc;                                               \
  } while (0)

  PkU SA, SB, SC, SD;
  // prologue: chunks 0,1 in flight (80 outstanding)
  STAGE(0, 0); STAGE(1, 1);

  // chunk c lives in buffer c%3; body(ch): wait ch resident, stage ch+2.
  // Waits always target loads issued TWO bodies earlier (~2 chunk-times).
  int ch = 0;
  for (int g = 0; g < 170; ++g, ch += 3) {   // chunks 0..509
    WAIT40; STAGE(ch + 2, 2); RUN8(0);
    WAIT40; STAGE(ch + 3, 0); RUN8(1);
    WAIT40; STAGE(ch + 4, 1); RUN8(2);
  }
  WAIT40; RUN8(0);   // chunk 510 (511's 40 loads stay outstanding)
  WAIT0;  RUN7(1);   // chunk 511: t = 4089..4095

  bsum[b] = acc;
#undef PREF
#undef STAGE
#undef WAIT40
#undef WAIT0
#undef RUN8
#undef RUN7
}

// ---- fallback (no workspace): inline params, no staging ----
__global__ __launch_bounds__(64, 1) void k_sim_fb(
    const float* __restrict__ logits,
    const float* __restrict__ u1, const float* __restrict__ u2,
    const float* __restrict__ u3, const float* __restrict__ u4,
    const float* __restrict__ mxM, const float* __restrict__ mnM,
    const float* __restrict__ labels,
    const float* __restrict__ hoverp, double* __restrict__ bsum) {
  int b = blockIdx.x * 64 + threadIdx.x;
  float hv = hoverp[0];
  Carry c;
  c.xz = 0.f; c.q0 = 1.f; c.q1 = 0.f; c.q2 = 0.f; c.q3 = 0.f;
  c.zd = 0.f; c.pv = 0.f; c.qv = 0.f; c.rv = 0.f;
  c.w1 = hv; c.w2 = hv; c.w3 = hv; c.w4 = hv;
  c.wd1 = 0.f; c.wd2 = 0.f; c.wd3 = 0.f; c.wd4 = 0.f;
  float l0 = labels[b];
  double acc = (double)l0 * (double)l0;
  for (int t = 1; t < T_STEPS; ++t) {
    Pk p = computePk((size_t)t * B_N + b, logits, u1, u2, u3, u4, mxM, mnM, labels);
    float facc = 0.f;
    stepOne(c, p, facc);
    acc += (double)facc;
  }
  bsum[b] = acc;
}

// ---- kernel 5: final deterministic reduce ----
__global__ void k_final(const double* __restrict__ bsum, float* __restrict__ out) {
  __shared__ double sm[512];
  sm[threadIdx.x] = bsum[threadIdx.x];
  __syncthreads();
  for (int s = 256; s; s >>= 1) {
    if (threadIdx.x < s) sm[threadIdx.x] += sm[threadIdx.x + s];
    __syncthreads();
  }
  if (threadIdx.x == 0) out[0] = (float)(sm[0] * (1.0 / 2097152.0));
}

extern "C" void kernel_launch(void* const* d_in, const int* in_sizes, int n_in,
                              void* d_out, int out_size, void* d_ws, size_t ws_size,
                              hipStream_t stream) {
  const float* labels = (const float*)d_in[0];
  const float* logits = (const float*)d_in[1];
  const float* u1 = (const float*)d_in[2];
  const float* u2 = (const float*)d_in[3];
  const float* u3 = (const float*)d_in[4];
  const float* u4 = (const float*)d_in[5];
  const float* mxM = (const float*)d_in[6];
  const float* mnM = (const float*)d_in[7];
  float* out = (float*)d_out;

  char* ws = (char*)d_ws;
  float*  hover   = (float*)(ws);
  float*  partial = (float*)(ws + 256);
  double* bsum    = (double*)(ws + 8192);
  Pk*     pack    = (Pk*)(ws + 16384);
  size_t need = 16384 + (size_t)T_STEPS * B_N * sizeof(Pk);
  bool pre = (ws_size >= need);

  k_kth  <<<1024, 256, 0, stream>>>(logits, partial);
  k_hover<<<1, 1024, 0, stream>>>(partial, hover);
  if (pre) {
    k_pre<<<8192, 256, 0, stream>>>(logits, u1, u2, u3, u4, mxM, mnM, labels, pack);
    k_sim3<<<8, 64, 0, stream>>>(pack, labels, hover, bsum);
  } else {
    k_sim_fb<<<8, 64, 0, stream>>>(logits, u1, u2, u3, u4, mxM, mnM, labels, hover, bsum);
  }
  k_final<<<1, 512, 0, stream>>>(bsum, out);
}

// Round 7
// 1437.851 us; speedup vs baseline: 1.2469x; 1.0407x over previous
//
#include <hip/hip_runtime.h>
#include <math.h>

#define T_STEPS 4096
#define B_N     512

// 20 floats = 80 bytes, five float4 loads per (t,b) step.
struct alignas(16) Pk {
  float KU1, KU2, KU3, KU4;   // kp*u_i/tau2^2
  float A,   mn,  mx,  cthr;  // A=-2*damp*tau2 ; cthr = tau*kTh/mB
  float cdym, cdxm, cq, cdx;  // tau*kTh*dym/IBxx ; tau*kTh*dxm/IByy ; tau*kTo/IBzz ; tau*Cd/mB
  float cA,  cB,  cC,  cD;    // tau*(IByy-IBzz)/IBxx ; tau*uP*IRzz/IBxx ; tau*(IBzz-IBxx)/IByy ; tau*uP*IRzz/IByy
  float cE,  label, pad0, pad1; // tau*(IBxx-IByy)/IBzz
};

union PkU { Pk p; float4 v[5]; };

__device__ __forceinline__ float sc_ref(float g, float base) {
  return (1.0f + (0.5f - g) * 0.95f) * base;
}

__device__ __forceinline__ Pk computePk(size_t i,
    const float* __restrict__ logits,
    const float* __restrict__ u1, const float* __restrict__ u2,
    const float* __restrict__ u3, const float* __restrict__ u4,
    const float* __restrict__ mxM, const float* __restrict__ mnM,
    const float* __restrict__ labels) {
  const float4* lg = (const float4*)logits + i * 3;
  float4 l0 = lg[0], l1 = lg[1], l2 = lg[2];
  float dxm  = sc_ref(l0.x, 0.16f);
  float dym  = sc_ref(l0.y, 0.16f);
  float IBxx = sc_ref(l0.w, 0.0123f);
  float IByy = sc_ref(l1.x, 0.0123f);
  float IBzz = sc_ref(l1.y, 0.0123f);
  float Cd   = sc_ref(l1.z, 0.1f);
  float kTh  = sc_ref(l1.w, 1.076e-05f);
  float kTo  = sc_ref(l2.x, 1.632e-07f);
  float tau2 = sc_ref(l2.y, 0.015f);
  float kp   = sc_ref(l2.z, 1.0f);
  float damp = sc_ref(l2.w, 1.0f);
  const float tau = 0.005f;
  const float tauOverMb = tau / 1.2f;
  Pk p;
  float K = kp / (tau2 * tau2);
  p.KU1 = K * u1[i];  p.KU2 = K * u2[i];  p.KU3 = K * u3[i];  p.KU4 = K * u4[i];
  p.A   = -2.0f * damp * tau2;
  p.mn  = mnM[i];  p.mx = mxM[i];
  p.cthr = kTh * tauOverMb;
  float tx = tau / IBxx, ty = tau / IByy, tz = tau / IBzz;
  p.cdym = kTh * dym * tx;
  p.cdxm = kTh * dxm * ty;
  p.cq   = kTo * tz;
  p.cdx  = Cd * tauOverMb;
  p.cA = (IByy - IBzz) * tx;
  p.cB = 1e-04f * tx;
  p.cC = (IBzz - IBxx) * ty;
  p.cD = 1e-04f * ty;
  p.cE = (IBxx - IByy) * tz;
  p.label = labels[i];
  p.pad0 = 0.f; p.pad1 = 0.f;
  return p;
}

struct Carry {
  float xz, q0, q1, q2, q3, zd, pv, qv, rv;
  float w1, w2, w3, w4, wd1, wd2, wd3, wd4;
};

__device__ __forceinline__ void stepOne(Carry& c, const Pk& p, float& facc) {
  const float TAU = 0.005f, HTAU = 0.0025f, TAUG = 0.04905f;
  float wdd1 = fmaf(p.A, c.wd1, p.KU1) - c.w1;
  float wdd2 = fmaf(p.A, c.wd2, p.KU2) - c.w2;
  float wdd3 = fmaf(p.A, c.wd3, p.KU3) - c.w3;
  float wdd4 = fmaf(p.A, c.wd4, p.KU4) - c.w4;
  float w1c = fminf(fmaxf(c.w1, p.mn), p.mx);
  float w2c = fminf(fmaxf(c.w2, p.mn), p.mx);
  float w3c = fminf(fmaxf(c.w3, p.mn), p.mx);
  float w4c = fminf(fmaxf(c.w4, p.mn), p.mx);
  float s1 = w1c * w1c, s2 = w2c * w2c, s3 = w3c * w3c, s4 = w4c * w4c;
  float sA = s1 + s3, sB = s2 + s4;
  float ssum = sA + sB;
  float dymd = (s1 + s4) - (s2 + s3);
  float dxmd = (s1 + s2) - (s3 + s4);
  float dqd  = sB - sA;
  float Thr2 = p.cthr * ssum;
  float qq = fmaf(c.q0, c.q0, c.q3 * c.q3) - fmaf(c.q1, c.q1, c.q2 * c.q2);
  float zdm = c.zd * fabsf(c.zd);
  float nzd = fmaf(-p.cdx, zdm, c.zd);
  nzd = fmaf(Thr2, qq, nzd) - TAUG;
  float t0 = fmaf(c.pv, c.q1, fmaf(c.qv, c.q2,  c.rv * c.q3));
  float t1 = fmaf(c.pv, c.q0, fmaf(-c.qv, c.q3, c.rv * c.q2));
  float t2 = fmaf(c.pv, c.q3, fmaf(c.qv, c.q0, -(c.rv * c.q1)));
  float t3 = fmaf(-c.pv, c.q2, fmaf(c.qv, c.q1, c.rv * c.q0));
  float nq0 = fmaf(-HTAU, t0, c.q0);
  float nq1 = fmaf( HTAU, t1, c.q1);
  float nq2 = fmaf( HTAU, t2, c.q2);
  float nq3 = fmaf( HTAU, t3, c.q3);
  float wsum = (w1c - w2c) + (w3c - w4c);
  float npv = fmaf(p.cA, c.qv * c.rv, c.pv);
  npv = fmaf(-p.cB, wsum * c.qv, npv);
  npv = fmaf(p.cdym, dymd, npv);
  float nqv = fmaf(p.cC, c.pv * c.rv, c.qv);
  nqv = fmaf(p.cD, wsum * c.pv, nqv);
  nqv = fmaf(p.cdxm, dxmd, nqv);
  float nrv = fmaf(p.cE, c.pv * c.qv, c.rv);
  nrv = fmaf(p.cq, dqd, nrv);
  float nxz = fmaf(TAU, nzd, c.xz);
  float d = nxz - c.xz;
  // |d|<=400 is false for NaN/Inf nxz, so it subsumes the isfinite check
  bool ok = (fabsf(d) <= 400.0f);
  float xznew = ok ? nxz : c.xz;
  float e = xznew - p.label;
  facc = fmaf(e, e, facc);
  c.w1 = fmaf(TAU, c.wd1, w1c);
  c.w2 = fmaf(TAU, c.wd2, w2c);
  c.w3 = fmaf(TAU, c.wd3, w3c);
  c.w4 = fmaf(TAU, c.wd4, w4c);
  c.wd1 = fmaf(TAU, wdd1, c.wd1);
  c.wd2 = fmaf(TAU, wdd2, c.wd2);
  c.wd3 = fmaf(TAU, wdd3, c.wd3);
  c.wd4 = fmaf(TAU, wdd4, c.wd4);
  c.q0 = nq0; c.q1 = nq1; c.q2 = nq2; c.q3 = nq3;
  c.pv = npv; c.qv = nqv; c.rv = nrv;
  c.zd = nzd; c.xz = xznew;
}

__device__ __forceinline__ void gload_lds16(const void* g, void* l) {
  __builtin_amdgcn_global_load_lds(
      (const __attribute__((address_space(1))) void*)g,
      (__attribute__((address_space(3))) void*)l, 16, 0, 0);
}

// ---- kernel 1: partial sums of kTh over T*B (deterministic tree) ----
__global__ void k_kth(const float* __restrict__ logits, float* __restrict__ partial) {
  __shared__ float sm[256];
  float a = 0.f;
  const int n = T_STEPS * B_N;
  for (int i = blockIdx.x * 256 + threadIdx.x; i < n; i += 1024 * 256)
    a += (1.0f + (0.5f - logits[(size_t)i * 12 + 7]) * 0.95f) * 1.076e-05f;
  sm[threadIdx.x] = a; __syncthreads();
  for (int s = 128; s; s >>= 1) {
    if (threadIdx.x < s) sm[threadIdx.x] += sm[threadIdx.x + s];
    __syncthreads();
  }
  if (threadIdx.x == 0) partial[blockIdx.x] = sm[0];
}

// ---- kernel 2: finalize hover ----
__global__ void k_hover(const float* __restrict__ partial, float* __restrict__ hover) {
  __shared__ float sm[1024];
  sm[threadIdx.x] = partial[threadIdx.x];
  __syncthreads();
  for (int s = 512; s; s >>= 1) {
    if (threadIdx.x < s) sm[threadIdx.x] += sm[threadIdx.x + s];
    __syncthreads();
  }
  if (threadIdx.x == 0) {
    float mean = sm[0] * (1.0f / 2097152.0f);
    float h = 1.2f * 9.81f / (4.0f * mean + 1e-12f);
    hover[0] = sqrtf(fmaxf(h, 1e-06f));
  }
}

// ---- kernel 3: per-(t,b) parameter precompute (fully parallel) ----
__global__ void k_pre(const float* __restrict__ logits,
                      const float* __restrict__ u1, const float* __restrict__ u2,
                      const float* __restrict__ u3, const float* __restrict__ u4,
                      const float* __restrict__ mxM, const float* __restrict__ mnM,
                      const float* __restrict__ labels, Pk* __restrict__ pack) {
  size_t i = (size_t)blockIdx.x * 256 + threadIdx.x;  // 8192*256 == T*B exactly
  PkU u;
  u.p = computePk(i, logits, u1, u2, u3, u4, mxM, mnM, labels);
  float4* dst = (float4*)(pack + i);
  #pragma unroll
  for (int k = 0; k < 5; ++k) dst[k] = u.v[k];
}

// ---- kernel 4: serial scan; 4-step groups, 4 LDS buffers, DMA issue
//      spread 5-loads-per-step (tests LDS-DMA queue-burst-stall theory) ----
__global__ __launch_bounds__(64, 1) void k_sim4(
    const Pk* __restrict__ pack,
    const float* __restrict__ labels,
    const float* __restrict__ hoverp, double* __restrict__ bsum) {
  __shared__ float4 lds[4 * 4 * 5 * 64];   // 80 KB: (((buf*4+slot)*5+k)*64+lane)
  const int lane = threadIdx.x;
  const int b = blockIdx.x * 64 + lane;    // 8 blocks x 64 lanes = 512
  float hv = hoverp[0];
  Carry c;
  c.xz = 0.f; c.q0 = 1.f; c.q1 = 0.f; c.q2 = 0.f; c.q3 = 0.f;
  c.zd = 0.f; c.pv = 0.f; c.qv = 0.f; c.rv = 0.f;
  c.w1 = hv; c.w2 = hv; c.w3 = hv; c.w4 = hv;
  c.wd1 = 0.f; c.wd2 = 0.f; c.wd3 = 0.f; c.wd4 = 0.f;
  float l0 = labels[b];
  double acc = (double)l0 * (double)l0;    // t=0 term: pred_z[0]=0

  const char* packb = (const char*)pack + (size_t)b * sizeof(Pk);

// ds_read set SET <- lds[BUF][SLOT][k][lane]; BUF/SLOT compile-time.
#define PREF(SET, BUF, SLOT) do {                                      \
    _Pragma("unroll")                                                  \
    for (int k = 0; k < 5; ++k)                                        \
      (SET).v[k] = lds[((((BUF)*4+(SLOT))*5)+k)*64 + lane];            \
  } while (0)

// stage ONE step: 5 async DMA loads of step (group SG, slot S) -> buf SBUF.
// t is wave-uniform (SALU math); clamp covers the final padded slot.
#define STG5(SG, S, SBUF) do {                                         \
    int t = 1 + (SG)*4 + (S); t = (t > T_STEPS-1) ? (T_STEPS-1) : t;   \
    const char* src = packb + (size_t)t * (B_N * sizeof(Pk));          \
    _Pragma("unroll")                                                  \
    for (int k = 0; k < 5; ++k)                                        \
      gload_lds16(src + 16*k, (void*)&lds[((((SBUF)*4+(S))*5)+k)*64]); \
  } while (0)

#define WAITN(N) do { asm volatile("s_waitcnt vmcnt(" #N ")" ::: "memory"); \
                      __builtin_amdgcn_sched_barrier(0); } while (0)

// Process group in buf GBUF (4 steps) while staging group SG into buf SBUF,
// one step's 5 loads interleaved before each compute step.
// On entry: 60 outstanding (this group + 2 newer); WAITN(40) -> resident.
#define GROUP4(GBUF, SG, SBUF) do {                                    \
    WAITN(40);                                                         \
    float facc = 0.f;                                                  \
    PREF(SA,GBUF,0); PREF(SB,GBUF,1); PREF(SC,GBUF,2);                 \
    STG5(SG, 0, SBUF); stepOne(c, SA.p, facc);                         \
    PREF(SD,GBUF,3);                                                   \
    STG5(SG, 1, SBUF); stepOne(c, SB.p, facc);                         \
    STG5(SG, 2, SBUF); stepOne(c, SC.p, facc);                         \
    STG5(SG, 3, SBUF); stepOne(c, SD.p, facc);                         \
    acc += (double)facc;                                               \
  } while (0)

// Same but no staging; wait count N = 20*(groups still outstanding after this one)
#define GROUP4N(GBUF, N) do {                                          \
    WAITN(N);                                                          \
    float facc = 0.f;                                                  \
    PREF(SA,GBUF,0); PREF(SB,GBUF,1); PREF(SC,GBUF,2);                 \
    stepOne(c, SA.p, facc);                                            \
    PREF(SD,GBUF,3);                                                   \
    stepOne(c, SB.p, facc);                                            \
    stepOne(c, SC.p, facc);                                            \
    stepOne(c, SD.p, facc);                                            \
    acc += (double)facc;                                               \
  } while (0)

  PkU SA, SB, SC, SD;
  // prologue: groups 0,1,2 -> bufs 0,1,2 (60 outstanding, < 63 HW limit)
  STG5(0,0,0); STG5(0,1,0); STG5(0,2,0); STG5(0,3,0);
  STG5(1,0,1); STG5(1,1,1); STG5(1,2,1); STG5(1,3,1);
  STG5(2,0,2); STG5(2,1,2); STG5(2,2,2); STG5(2,3,2);

  // groups 0..1019 in the main loop (255 x 4), each stages group g+3.
  // group g lives in buf g%4; steps t = 1+4g .. 4+4g.
  int g = 0;
  for (int it = 0; it < 255; ++it, g += 4) {
    GROUP4(0, g+3, 3);
    GROUP4(1, g+4, 0);
    GROUP4(2, g+5, 1);
    GROUP4(3, g+6, 2);
  }
  // g == 1020: process 1020 (buf 0), stage final group 1023 (buf 3)
  GROUP4(0, 1023, 3);
  GROUP4N(1, 40);   // group 1021 (1022,1023 outstanding)
  GROUP4N(2, 20);   // group 1022 (1023 outstanding)
  { // group 1023 (buf 3): t = 4093,4094,4095 in slots 0..2 (slot 3 is pad)
    WAITN(0);
    float facc = 0.f;
    PREF(SA,3,0); PREF(SB,3,1); PREF(SC,3,2);
    stepOne(c, SA.p, facc);
    stepOne(c, SB.p, facc);
    stepOne(c, SC.p, facc);
    acc += (double)facc;
  }
  bsum[b] = acc;
#undef PREF
#undef STG5
#undef WAITN
#undef GROUP4
#undef GROUP4N
}

// ---- fallback (no workspace): inline params, no staging ----
__global__ __launch_bounds__(64, 1) void k_sim_fb(
    const float* __restrict__ logits,
    const float* __restrict__ u1, const float* __restrict__ u2,
    const float* __restrict__ u3, const float* __restrict__ u4,
    const float* __restrict__ mxM, const float* __restrict__ mnM,
    const float* __restrict__ labels,
    const float* __restrict__ hoverp, double* __restrict__ bsum) {
  int b = blockIdx.x * 64 + threadIdx.x;
  float hv = hoverp[0];
  Carry c;
  c.xz = 0.f; c.q0 = 1.f; c.q1 = 0.f; c.q2 = 0.f; c.q3 = 0.f;
  c.zd = 0.f; c.pv = 0.f; c.qv = 0.f; c.rv = 0.f;
  c.w1 = hv; c.w2 = hv; c.w3 = hv; c.w4 = hv;
  c.wd1 = 0.f; c.wd2 = 0.f; c.wd3 = 0.f; c.wd4 = 0.f;
  float l0 = labels[b];
  double acc = (double)l0 * (double)l0;
  for (int t = 1; t < T_STEPS; ++t) {
    Pk p = computePk((size_t)t * B_N + b, logits, u1, u2, u3, u4, mxM, mnM, labels);
    float facc = 0.f;
    stepOne(c, p, facc);
    acc += (double)facc;
  }
  bsum[b] = acc;
}

// ---- kernel 5: final deterministic reduce ----
__global__ void k_final(const double* __restrict__ bsum, float* __restrict__ out) {
  __shared__ double sm[512];
  sm[threadIdx.x] = bsum[threadIdx.x];
  __syncthreads();
  for (int s = 256; s; s >>= 1) {
    if (threadIdx.x < s) sm[threadIdx.x] += sm[threadIdx.x + s];
    __syncthreads();
  }
  if (threadIdx.x == 0) out[0] = (float)(sm[0] * (1.0 / 2097152.0));
}

extern "C" void kernel_launch(void* const* d_in, const int* in_sizes, int n_in,
                              void* d_out, int out_size, void* d_ws, size_t ws_size,
                              hipStream_t stream) {
  const float* labels = (const float*)d_in[0];
  const float* logits = (const float*)d_in[1];
  const float* u1 = (const float*)d_in[2];
  const float* u2 = (const float*)d_in[3];
  const float* u3 = (const float*)d_in[4];
  const float* u4 = (const float*)d_in[5];
  const float* mxM = (const float*)d_in[6];
  const float* mnM = (const float*)d_in[7];
  float* out = (float*)d_out;

  char* ws = (char*)d_ws;
  float*  hover   = (float*)(ws);
  float*  partial = (float*)(ws + 256);
  double* bsum    = (double*)(ws + 8192);
  Pk*     pack    = (Pk*)(ws + 16384);
  size_t need = 16384 + (size_t)T_STEPS * B_N * sizeof(Pk);
  bool pre = (ws_size >= need);

  k_kth  <<<1024, 256, 0, stream>>>(logits, partial);
  k_hover<<<1, 1024, 0, stream>>>(partial, hover);
  if (pre) {
    k_pre<<<8192, 256, 0, stream>>>(logits, u1, u2, u3, u4, mxM, mnM, labels, pack);
    k_sim4<<<8, 64, 0, stream>>>(pack, labels, hover, bsum);
  } else {
    k_sim_fb<<<8, 64, 0, stream>>>(logits, u1, u2, u3, u4, mxM, mnM, labels, hover, bsum);
  }
  k_final<<<1, 512, 0, stream>>>(bsum, out);
}